// Round 12
// baseline (226.253 us; speedup 1.0000x reference)
//
#include <hip/hip_runtime.h>
#include <hip/hip_bf16.h>

#define N_NODES 122880
#define N_EDGES 983040
#define NBKT 480      // buckets of 256 nodes
#define BCAP 2560     // per-bucket edge capacity for adj (mean 2048)
#define EPB 4096      // edges per pass-1 block
#define NPB 240       // pass-1 blocks (N_EDGES / EPB)
#define SEGCAP 40     // per-(bucket,block) segment capacity (mean 8.5, 10+sig)
#define NPAD 1792     // Wfc N padded to 14*128 for 128x128 GEMM tiles

typedef __hip_bfloat16 bf16;
typedef __attribute__((ext_vector_type(8))) short short8;
typedef __attribute__((ext_vector_type(4))) float floatx4;

__device__ __forceinline__ void gl_lds16(const void* g, void* l) {
    __builtin_amdgcn_global_load_lds(
        (const __attribute__((address_space(1))) void*)g,
        (__attribute__((address_space(3))) void*)l, 16, 0, 0);
}

__device__ __forceinline__ float bflo(unsigned u) {
    return __uint_as_float(u << 16);
}
__device__ __forceinline__ float bfhi(unsigned u) {
    return __uint_as_float(u & 0xffff0000u);
}

// ---- merged pass 1: psort (blocks 0..239) + convw (240..303) +
//      transWfc (304..3663).
// psort: per-(bucket,block) PRIVATE segments -- no global cursor, no
// global atomics, no memset slot.
__global__ __launch_bounds__(256) void k_psort_prep(
        const int* __restrict__ ei, unsigned short* __restrict__ cnt,
        unsigned* __restrict__ gbuf,
        const float* __restrict__ W1, const float* __restrict__ W2,
        const float* __restrict__ Wfc,
        bf16* __restrict__ W1T, bf16* __restrict__ W2T,
        bf16* __restrict__ WfcT) {
    __shared__ __align__(16) char smem[4352];
    const int b = blockIdx.x, t = threadIdx.x;
    if (b < NPB) {                       // ---- psort ----
        int* cur = (int*)smem;           // NBKT ints
        for (int i = t; i < NBKT; i += 256) cur[i] = 0;
        __syncthreads();
        const int base = b * EPB;
        unsigned pay[16];
        short bk[16], pib[16];
#pragma unroll
        for (int j = 0; j < 16; ++j) {
            int e = base + j * 256 + t;
            int d = ei[N_EDGES + e];
            int s = ei[e];
            bk[j] = (short)(d >> 8);
            pay[j] = (unsigned)(d & 255) | ((unsigned)s << 8);
            pib[j] = (short)atomicAdd(&cur[d >> 8], 1);
        }
#pragma unroll
        for (int j = 0; j < 16; ++j) {
            if (pib[j] < SEGCAP)
                gbuf[((unsigned)bk[j] * NPB + b) * SEGCAP + pib[j]] = pay[j];
        }
        __syncthreads();                 // histogram complete
        for (int i = t; i < NBKT; i += 256) {
            int c = cur[i];
            if (c > SEGCAP) c = SEGCAP;
            cnt[i * NPB + b] = (unsigned short)c;
        }
    } else if (b < NPB + 64) {           // ---- convw ----
        int u = (b - NPB) * 256 + t;
        if (u < 64 * 128) {              // W1 [64][128] -> W1T [128][64]
            int k = u >> 7, n = u & 127;
            W1T[n * 64 + k] = __float2bfloat16(W1[u]);
        } else {                         // W2 [128][64] -> W2T [64][128]
            int v = u - 64 * 128;
            int k = v >> 6, n = v & 63;
            W2T[n * 128 + k] = __float2bfloat16(W2[v]);
        }
    } else {                             // ---- transWfc ----
        float (*ts)[33] = (float(*)[33])smem;
        const int bid2 = b - (NPB + 64);
        const int n0 = (bid2 % 56) * 32, k0 = (bid2 / 56) * 32;
        const int tx = t & 31, ty = t >> 5;
        const bool nok = (n0 + tx) < 1728;
#pragma unroll
        for (int j = 0; j < 4; ++j)
            ts[ty + j * 8][tx] =
                nok ? Wfc[(long)(k0 + ty + j * 8) * 1728 + n0 + tx] : 0.0f;
        __syncthreads();
#pragma unroll
        for (int j = 0; j < 4; ++j)
            WfcT[(long)(n0 + ty + j * 8) * 1920 + k0 + tx] =
                __float2bfloat16(ts[tx][ty + j * 8]);
    }
}

// ---- pass 2: per-bucket CSR build + dinv + FUSED x->bf16 pre-scale --------
__global__ __launch_bounds__(256) void k_bcsr(
        const unsigned short* __restrict__ cnt,
        const unsigned* __restrict__ gbuf,
        int* __restrict__ adj, unsigned* __restrict__ co,
        float* __restrict__ dinv,
        const float* __restrict__ x, bf16* __restrict__ xb) {
    __shared__ int hist[256];
    __shared__ int arr[256];
    __shared__ int exc[256];
    __shared__ int soff[256];
    __shared__ float dinvs[256];
    const int b = blockIdx.x, t = threadIdx.x;
    hist[t] = 0;

    // segment counts scan (240 segments, exclusive offsets in soff)
    const int myc = (t < NPB) ? (int)cnt[b * NPB + t] : 0;
    arr[t] = myc;
    __syncthreads();
    for (int d = 1; d < 256; d <<= 1) {
        int v = (t >= d) ? arr[t - d] : 0;
        __syncthreads();
        arr[t] += v;
        __syncthreads();
    }
    soff[t] = arr[t] - myc;
    __syncthreads();
    int E = arr[255];
    if (E > BCAP) E = BCAP;

    int dl[10], sv[10];
    short pb[10];
    int n = 0;
    for (int idx = t; idx < E; idx += 256) {
        int lo = 0, hi = NPB - 1;            // find seg: soff[lo] <= idx
        while (lo < hi) {
            int mid = (lo + hi + 1) >> 1;
            if (soff[mid] <= idx) lo = mid; else hi = mid - 1;
        }
        unsigned p = gbuf[((unsigned)b * NPB + lo) * SEGCAP + (idx - soff[lo])];
        dl[n] = p & 255;
        sv[n] = (int)(p >> 8);
        pb[n] = (short)atomicAdd(&hist[dl[n]], 1);
        ++n;
    }
    __syncthreads();
    const int cnt_t = hist[t];
    arr[t] = cnt_t;
    __syncthreads();
    for (int d = 1; d < 256; d <<= 1) {      // dest-local inclusive scan
        int v = (t >= d) ? arr[t - d] : 0;
        __syncthreads();
        arr[t] += v;
        __syncthreads();
    }
    const int ex = arr[t] - cnt_t;           // exclusive offset
    exc[t] = ex;
    const int node = b * 256 + t;
    co[node] = ((unsigned)ex << 16) | (unsigned)cnt_t;
    const float di = rsqrtf((float)cnt_t + 1.0f);
    dinv[node] = di;
    dinvs[t] = di;
    __syncthreads();
    for (int j = 0; j < n; ++j)
        adj[b * BCAP + exc[dl[j]] + pb[j]] = sv[j];

    // fused convert: this block's 256 node rows, 4 floats/thread/iter
    const long xbase = (long)b * 256 * 64;
    for (int r = 0; r < 16; ++r) {
        int u = r * 256 + t;                 // 0..4095
        int nl = u >> 4;                     // node-local
        const float4 v = ((const float4*)(x + xbase))[u];
        const float d2 = dinvs[nl];
        bf16* o = xb + xbase + u * 4;
        o[0] = __float2bfloat16(d2 * v.x);
        o[1] = __float2bfloat16(d2 * v.y);
        o[2] = __float2bfloat16(d2 * v.z);
        o[3] = __float2bfloat16(d2 * v.w);
    }
}

// ------- aggregation on pre-scaled features: out = di*(self + sum nbrs) -----
// v4: each 16-lane group owns TWO nodes and interleaves their neighbor
// batches -> 16 REAL loads in flight (vs 8), no junk issue for the common
// degree ~8 case. Doubles memory-level parallelism of the random gather.
template <bool BIAS_RELU>
__global__ __launch_bounds__(256) void k_agg(const bf16* __restrict__ xb,
                                             const float* __restrict__ dinv,
                                             const unsigned* __restrict__ co,
                                             const int* __restrict__ adj,
                                             const float* __restrict__ bias,
                                             bf16* __restrict__ out) {
    const int wave = threadIdx.x >> 6, lane = threadIdx.x & 63;
    const int sub = lane >> 4, l16 = lane & 15;
    const int nodeA = blockIdx.x * 32 + wave * 8 + sub;
    const int nodeB = nodeA + 4;

    const float diA = dinv[nodeA], diB = dinv[nodeB];
    const unsigned cA_ = co[nodeA], cB_ = co[nodeB];
    int cA = (int)(cA_ & 0xffffu); if (cA > 32) cA = 32;
    int cB = (int)(cB_ & 0xffffu); if (cB > 32) cB = 32;
    const int* alA = adj + (nodeA >> 8) * BCAP + (cA_ >> 16);
    const int* alB = adj + (nodeB >> 8) * BCAP + (cB_ >> 16);
    int slA  = (l16 < cA)      ? alA[l16]      : 0;
    int slA2 = (16 + l16 < cA) ? alA[16 + l16] : 0;
    int slB  = (l16 < cB)      ? alB[l16]      : 0;
    int slB2 = (16 + l16 < cB) ? alB[16 + l16] : 0;

    const uint2 usA = *(const uint2*)(xb + ((long)nodeA << 6) + (l16 << 2));
    const uint2 usB = *(const uint2*)(xb + ((long)nodeB << 6) + (l16 << 2));
    float a0 = bflo(usA.x), a1 = bfhi(usA.x);
    float a2 = bflo(usA.y), a3 = bfhi(usA.y);
    float b0 = bflo(usB.x), b1v = bfhi(usB.x);
    float b2v = bflo(usB.y), b3 = bfhi(usB.y);

    const int cm = (cA > cB) ? cA : cB;
    for (int p0 = 0; p0 < cm; p0 += 8) {
        const int svA = (p0 < 16) ? slA : slA2;
        const int svB = (p0 < 16) ? slB : slB2;
        uint2 uA[8], uB[8];
#pragma unroll
        for (int j = 0; j < 8; ++j) {        // A-batch issue
            int p = p0 + j;
            bool ok = p < cA;                // uniform within 16-lane group
            int s = __shfl(svA, p & 15, 16);
            uint2 u = *(const uint2*)(xb + ((long)s << 6) + (l16 << 2));
            uA[j].x = ok ? u.x : 0u;
            uA[j].y = ok ? u.y : 0u;
        }
#pragma unroll
        for (int j = 0; j < 8; ++j) {        // B-batch issue (overlaps A)
            int p = p0 + j;
            bool ok = p < cB;
            int s = __shfl(svB, p & 15, 16);
            uint2 u = *(const uint2*)(xb + ((long)s << 6) + (l16 << 2));
            uB[j].x = ok ? u.x : 0u;
            uB[j].y = ok ? u.y : 0u;
        }
#pragma unroll
        for (int j = 0; j < 8; ++j) {
            a0 += bflo(uA[j].x); a1 += bfhi(uA[j].x);
            a2 += bflo(uA[j].y); a3 += bfhi(uA[j].y);
            b0 += bflo(uB[j].x); b1v += bfhi(uB[j].x);
            b2v += bflo(uB[j].y); b3 += bfhi(uB[j].y);
        }
    }

    float rA[4] = {diA * a0, diA * a1, diA * a2, diA * a3};
    float rB[4] = {diB * b0, diB * b1v, diB * b2v, diB * b3};
    if (BIAS_RELU) {
#pragma unroll
        for (int k = 0; k < 4; ++k) {
            const float bv = bias[l16 * 4 + k];
            rA[k] = fmaxf(rA[k] + bv, 0.0f);
            rB[k] = fmaxf(rB[k] + bv, 0.0f);
        }
    }
    bf16* oA = out + ((long)nodeA << 6) + (l16 << 2);
    bf16* oB = out + ((long)nodeB << 6) + (l16 << 2);
#pragma unroll
    for (int k = 0; k < 4; ++k) {
        oA[k] = __float2bfloat16(rA[k]);
        oB[k] = __float2bfloat16(rB[k]);
    }
}

// -------- fused MLP: g = dinv (.) ( relu(xa@W1 + b1) @ W2 )  ----------------
__global__ __launch_bounds__(256) void k_mlp(const bf16* __restrict__ xa,
                                             const bf16* __restrict__ W1T,
                                             const bf16* __restrict__ W2T,
                                             const float* __restrict__ b1,
                                             const float* __restrict__ dinv,
                                             bf16* __restrict__ g) {
    __shared__ __align__(16) bf16 As[128 * 64];    // row&7 chunk-XOR swizzle
    __shared__ __align__(16) bf16 C1s[128 * 136];
    const int tid = threadIdx.x;
    const int wave = tid >> 6, lane = tid & 63;
    const int quad = lane >> 4, l16 = lane & 15;
    const int bm = blockIdx.x * 128;
    const int wm = (wave & 1) * 64;
    const int wn1 = (wave >> 1) * 64;
    const int wn2 = (wave >> 1) * 32;

#pragma unroll
    for (int q = 0; q < 4; ++q) {
        int G = q * 256 + tid;
        int gc = (G & ~7) | ((G & 7) ^ ((G >> 3) & 7));
        gl_lds16(xa + (long)bm * 64 + gc * 8, As + ((q * 4 + wave) * 64) * 8);
    }
    short8 w1f[2][4];
#pragma unroll
    for (int kc = 0; kc < 2; ++kc)
#pragma unroll
        for (int in = 0; in < 4; ++in)
            w1f[kc][in] = *(const short8*)(W1T + (wn1 + in * 16 + l16) * 64 +
                                           kc * 32 + quad * 8);
    floatx4 acc1[4][4];
#pragma unroll
    for (int i = 0; i < 4; ++i)
#pragma unroll
        for (int j = 0; j < 4; ++j) acc1[i][j] = (floatx4){0.f, 0.f, 0.f, 0.f};
    __syncthreads();

#pragma unroll
    for (int kc = 0; kc < 2; ++kc)
#pragma unroll
        for (int im = 0; im < 4; ++im) {
            const int R = wm + im * 16 + l16;
            short8 af = *(const short8*)(As + R * 64 +
                                         (((kc * 4 + quad) ^ (R & 7)) * 8));
#pragma unroll
            for (int in = 0; in < 4; ++in)
                acc1[im][in] = __builtin_amdgcn_mfma_f32_16x16x32_bf16(
                    af, w1f[kc][in], acc1[im][in], 0, 0, 0);
        }

#pragma unroll
    for (int in = 0; in < 4; ++in) {
        const int col = wn1 + in * 16 + l16;
        const float bv = b1[col];
#pragma unroll
        for (int im = 0; im < 4; ++im) {
            const int row = wm + im * 16 + quad * 4;
#pragma unroll
            for (int r = 0; r < 4; ++r)
                C1s[(row + r) * 136 + col] =
                    __float2bfloat16(fmaxf(acc1[im][in][r] + bv, 0.0f));
        }
    }
    short8 w2f[4][2];
#pragma unroll
    for (int kc = 0; kc < 4; ++kc)
#pragma unroll
        for (int in = 0; in < 2; ++in)
            w2f[kc][in] = *(const short8*)(W2T + (wn2 + in * 16 + l16) * 128 +
                                           kc * 32 + quad * 8);
    floatx4 acc2[4][2];
#pragma unroll
    for (int i = 0; i < 4; ++i)
#pragma unroll
        for (int j = 0; j < 2; ++j) acc2[i][j] = (floatx4){0.f, 0.f, 0.f, 0.f};
    __syncthreads();

#pragma unroll
    for (int kc = 0; kc < 4; ++kc)
#pragma unroll
        for (int im = 0; im < 4; ++im) {
            short8 af = *(const short8*)(C1s + (wm + im * 16 + l16) * 136 +
                                         kc * 32 + quad * 8);
#pragma unroll
            for (int in = 0; in < 2; ++in)
                acc2[im][in] = __builtin_amdgcn_mfma_f32_16x16x32_bf16(
                    af, w2f[kc][in], acc2[im][in], 0, 0, 0);
        }

    float dv[4][4];
#pragma unroll
    for (int im = 0; im < 4; ++im)
#pragma unroll
        for (int r = 0; r < 4; ++r)
            dv[im][r] = dinv[bm + wm + im * 16 + quad * 4 + r];

#pragma unroll
    for (int in = 0; in < 2; ++in) {
        const int col = wn2 + in * 16 + l16;
#pragma unroll
        for (int im = 0; im < 4; ++im) {
            const int row = bm + wm + im * 16 + quad * 4;
#pragma unroll
            for (int r = 0; r < 4; ++r)
                g[(long)(row + r) * 64 + col] =
                    __float2bfloat16(dv[im][r] * acc2[im][in][r]);
        }
    }
}

// ------ bf16 MFMA GEMM 128x128, BK=64 (half the barriers), 8 waves ----------
template <bool RELU, bool BIAS, typename OutT>
__global__ __launch_bounds__(512) void gemm_bt(const bf16* __restrict__ A,
                                               const bf16* __restrict__ BT,
                                               const float* __restrict__ bias,
                                               OutT* __restrict__ C,
                                               int M, int N, int K) {
    __shared__ __align__(16) bf16 As[2][128 * 64];
    __shared__ __align__(16) bf16 Bs[2][128 * 64];
    const int tid = threadIdx.x;
    const int wave = tid >> 6, lane = tid & 63;
    const int quad = lane >> 4, l16 = lane & 15;
    const int bid = blockIdx.x;
    const int bx = (bid & 7) * 4 + ((bid >> 3) & 3);   // M-tile
    const int by = bid >> 5;                           // N-tile
    const int bm = bx * 128, bn = by * 128;
    const int wm = (wave & 1) * 64, wn = (wave >> 1) * 32;

    floatx4 acc[4][2];
#pragma unroll
    for (int i = 0; i < 4; ++i)
#pragma unroll
        for (int j = 0; j < 2; ++j) acc[i][j] = (floatx4){0.f, 0.f, 0.f, 0.f};

    const int r8 = tid >> 3;   // row 0..63 (row+64 in second store)
    const int c8 = tid & 7;    // 16B chunk within 128B row
    const int slot = r8 * 64 + ((c8 ^ (r8 & 7)) * 8);   // shorts; (r8+64)&7==r8&7

    const bf16* gA0 = A + (long)(bm + r8) * K + c8 * 8;
    const bf16* gA1 = A + (long)(bm + r8 + 64) * K + c8 * 8;
    const bf16* gB0 = BT + (long)(bn + r8) * K + c8 * 8;
    const bf16* gB1 = BT + (long)(bn + r8 + 64) * K + c8 * 8;

    const int rsw = l16 & 7;
    const int NT = K >> 6;     // 30 K-steps of 64

    // ---- prologue: tile0 -> buf0; prefetch tile1 into regs ----
    uint4 ra0 = *(const uint4*)gA0;
    uint4 ra1 = *(const uint4*)gA1;
    uint4 rb0 = *(const uint4*)gB0;
    uint4 rb1 = *(const uint4*)gB1;
    *(uint4*)(As[0] + slot) = ra0;
    *(uint4*)(As[0] + 4096 + slot) = ra1;
    *(uint4*)(Bs[0] + slot) = rb0;
    *(uint4*)(Bs[0] + 4096 + slot) = rb1;
    ra0 = *(const uint4*)(gA0 + 64);
    ra1 = *(const uint4*)(gA1 + 64);
    rb0 = *(const uint4*)(gB0 + 64);
    rb1 = *(const uint4*)(gB1 + 64);
    __syncthreads();

    // regs hold tile t+1 at the top of step t; buf[t&1] holds tile t.
    for (int t = 0; t < NT; t += 2) {
        // ---- step t (even): compute buf0, write tile t+1 -> buf1 ----
        {
            short8 af[2][4], bfr[2][2];
#pragma unroll
            for (int kc = 0; kc < 2; ++kc) {
#pragma unroll
                for (int im = 0; im < 4; ++im)
                    af[kc][im] = *(const short8*)(
                        As[0] + (wm + im * 16 + l16) * 64 +
                        (((kc * 4 + quad) ^ rsw) * 8));
#pragma unroll
                for (int in = 0; in < 2; ++in)
                    bfr[kc][in] = *(const short8*)(
                        Bs[0] + (wn + in * 16 + l16) * 64 +
                        (((kc * 4 + quad) ^ rsw) * 8));
            }
            *(uint4*)(As[1] + slot) = ra0;            // tile t+1 (always exists)
            *(uint4*)(As[1] + 4096 + slot) = ra1;
            *(uint4*)(Bs[1] + slot) = rb0;
            *(uint4*)(Bs[1] + 4096 + slot) = rb1;
            if (t + 2 < NT) {                         // prefetch tile t+2
                ra0 = *(const uint4*)(gA0 + (t + 2) * 64);
                ra1 = *(const uint4*)(gA1 + (t + 2) * 64);
                rb0 = *(const uint4*)(gB0 + (t + 2) * 64);
                rb1 = *(const uint4*)(gB1 + (t + 2) * 64);
            }
#pragma unroll
            for (int kc = 0; kc < 2; ++kc)
#pragma unroll
                for (int im = 0; im < 4; ++im)
#pragma unroll
                    for (int in = 0; in < 2; ++in)
                        acc[im][in] = __builtin_amdgcn_mfma_f32_16x16x32_bf16(
                            af[kc][im], bfr[kc][in], acc[im][in], 0, 0, 0);
            __syncthreads();
        }
        // ---- step t+1 (odd): compute buf1, write tile t+2 -> buf0 ----
        {
            short8 af[2][4], bfr[2][2];
#pragma unroll
            for (int kc = 0; kc < 2; ++kc) {
#pragma unroll
                for (int im = 0; im < 4; ++im)
                    af[kc][im] = *(const short8*)(
                        As[1] + (wm + im * 16 + l16) * 64 +
                        (((kc * 4 + quad) ^ rsw) * 8));
#pragma unroll
                for (int in = 0; in < 2; ++in)
                    bfr[kc][in] = *(const short8*)(
                        Bs[1] + (wn + in * 16 + l16) * 64 +
                        (((kc * 4 + quad) ^ rsw) * 8));
            }
            if (t + 2 < NT) {                         // write tile t+2
                *(uint4*)(As[0] + slot) = ra0;
                *(uint4*)(As[0] + 4096 + slot) = ra1;
                *(uint4*)(Bs[0] + slot) = rb0;
                *(uint4*)(Bs[0] + 4096 + slot) = rb1;
            }
            if (t + 3 < NT) {                         // prefetch tile t+3
                ra0 = *(const uint4*)(gA0 + (t + 3) * 64);
                ra1 = *(const uint4*)(gA1 + (t + 3) * 64);
                rb0 = *(const uint4*)(gB0 + (t + 3) * 64);
                rb1 = *(const uint4*)(gB1 + (t + 3) * 64);
            }
#pragma unroll
            for (int kc = 0; kc < 2; ++kc)
#pragma unroll
                for (int im = 0; im < 4; ++im)
#pragma unroll
                    for (int in = 0; in < 2; ++in)
                        acc[im][in] = __builtin_amdgcn_mfma_f32_16x16x32_bf16(
                            af[kc][im], bfr[kc][in], acc[im][in], 0, 0, 0);
            __syncthreads();
        }
    }

#pragma unroll
    for (int in = 0; in < 2; ++in) {
        int gcol = bn + wn + in * 16 + l16;
        bool wok = gcol < N;
        float bv = (BIAS && wok) ? bias[gcol] : 0.0f;
#pragma unroll
        for (int im = 0; im < 4; ++im) {
            int mrow = bm + wm + im * 16 + quad * 4;
#pragma unroll
            for (int r = 0; r < 4; ++r) {
                float v = acc[im][in][r] + bv;
                if (RELU) v = fmaxf(v, 0.0f);
                if (wok) {
                    if constexpr (sizeof(OutT) == 2)
                        C[(long)(mrow + r) * N + gcol] = __float2bfloat16(v);
                    else
                        C[(long)(mrow + r) * N + gcol] = v;
                }
            }
        }
    }
}

// ---------------- driver (6 launches, no memset) ----------------
extern "C" void kernel_launch(void* const* d_in, const int* in_sizes, int n_in,
                              void* d_out, int out_size, void* d_ws, size_t ws_size,
                              hipStream_t stream) {
    const float* x   = (const float*)d_in[0];
    const int*   ei  = (const int*)d_in[1];
    const float* W1  = (const float*)d_in[2];
    const float* b1  = (const float*)d_in[3];
    const float* W2  = (const float*)d_in[4];
    const float* b2  = (const float*)d_in[5];
    const float* Wfc = (const float*)d_in[6];
    const float* bfc = (const float*)d_in[7];

    char* p = (char*)d_ws;
    unsigned short* cnt = (unsigned short*)p; p += (size_t)NBKT * NPB * 2; // 230400
    int*      adj  = (int*)p;      p += (size_t)NBKT * BCAP * 4;
    unsigned* co   = (unsigned*)p; p += (size_t)N_NODES * 4;
    float*    dinv = (float*)p;    p += (size_t)N_NODES * 4;
    bf16*     xb   = (bf16*)p;     p += (size_t)N_NODES * 64 * 2;
    // union: gbuf (18.43 MB, used by psort/bcsr only) overlays xa+g (31.4 MB)
    char* uni = p;
    unsigned* gbuf = (unsigned*)uni;                       // NBKT*NPB*SEGCAP*4
    bf16*     xa   = (bf16*)uni;
    bf16*     g    = (bf16*)(uni + (size_t)N_NODES * 64 * 2);
    p = uni + 2 * (size_t)N_NODES * 64 * 2;
    bf16*     h2   = (bf16*)p;     p += (size_t)N_NODES * 64 * 2;
    bf16*     W1T  = (bf16*)p;     p += 128 * 64 * 2;
    bf16*     W2T  = (bf16*)p;     p += 64 * 128 * 2;
    bf16*     WfcT = (bf16*)p;     p += (size_t)NPAD * 1920 * 2;

    // psort (private segments, no atomics) + convw + transWfc fused
    k_psort_prep<<<NPB + 64 + 3360, 256, 0, stream>>>(ei, cnt, gbuf,
                                                      W1, W2, Wfc,
                                                      W1T, W2T, WfcT);
    // CSR build + dinv + fused x->bf16 pre-scale (done with gbuf afterwards)
    k_bcsr<<<NBKT, 256, 0, stream>>>(cnt, gbuf, adj, co, dinv, x, xb);

    // xa = A_hat * x  (dual-node interleaved gather, 16 loads in flight)
    k_agg<false><<<N_NODES / 32, 256, 0, stream>>>(xb, dinv, co, adj, nullptr, xa);
    // g = dinv (.) ( relu(xa@W1 + b1) @ W2 )
    k_mlp<<<N_NODES / 128, 256, 0, stream>>>(xa, W1T, W2T, b1, dinv, g);
    // h2 = relu(di*(g[d]+sum g[s]) + b2)
    k_agg<true><<<N_NODES / 32, 256, 0, stream>>>(g, dinv, co, adj, b2, h2);
    // out = h2.reshape(4096,1920) @ Wfc + bfc  (XCD-affine 1-D grid: 32x14=448)
    gemm_bt<false, true, float><<<448, 512, 0, stream>>>(
        h2, WfcT, bfc, (float*)d_out, 4096, 1728, 1920);
}

// Round 13
// 218.205 us; speedup vs baseline: 1.0369x; 1.0369x over previous
//
#include <hip/hip_runtime.h>
#include <hip/hip_bf16.h>

#define N_NODES 122880
#define N_EDGES 983040
#define NBKT 480      // buckets of 256 nodes
#define BCAP 2560     // per-bucket edge capacity for adj (mean 2048)
#define EPB 4096      // edges per pass-1 block
#define NPB 240       // pass-1 blocks (N_EDGES / EPB)
#define SEGCAP 40     // per-(bucket,block) segment capacity (mean 8.5, 10+sig)
#define NPAD 1792     // Wfc N padded to 14*128 for 128x128 GEMM tiles

typedef __hip_bfloat16 bf16;
typedef __attribute__((ext_vector_type(8))) short short8;
typedef __attribute__((ext_vector_type(4))) float floatx4;

__device__ __forceinline__ void gl_lds16(const void* g, void* l) {
    __builtin_amdgcn_global_load_lds(
        (const __attribute__((address_space(1))) void*)g,
        (__attribute__((address_space(3))) void*)l, 16, 0, 0);
}

__device__ __forceinline__ float bflo(unsigned u) {
    return __uint_as_float(u << 16);
}
__device__ __forceinline__ float bfhi(unsigned u) {
    return __uint_as_float(u & 0xffff0000u);
}

// ---- merged pass 1: psort (blocks 0..239) + convw (240..303) +
//      transWfc (304..3663).
// psort: per-(bucket,block) PRIVATE segments -- no global cursor, no
// global atomics, no memset slot.
__global__ __launch_bounds__(256) void k_psort_prep(
        const int* __restrict__ ei, unsigned short* __restrict__ cnt,
        unsigned* __restrict__ gbuf,
        const float* __restrict__ W1, const float* __restrict__ W2,
        const float* __restrict__ Wfc,
        bf16* __restrict__ W1T, bf16* __restrict__ W2T,
        bf16* __restrict__ WfcT) {
    __shared__ __align__(16) char smem[4352];
    const int b = blockIdx.x, t = threadIdx.x;
    if (b < NPB) {                       // ---- psort ----
        int* cur = (int*)smem;           // NBKT ints
        for (int i = t; i < NBKT; i += 256) cur[i] = 0;
        __syncthreads();
        const int base = b * EPB;
        unsigned pay[16];
        short bk[16], pib[16];
#pragma unroll
        for (int j = 0; j < 16; ++j) {
            int e = base + j * 256 + t;
            int d = ei[N_EDGES + e];
            int s = ei[e];
            bk[j] = (short)(d >> 8);
            pay[j] = (unsigned)(d & 255) | ((unsigned)s << 8);
            pib[j] = (short)atomicAdd(&cur[d >> 8], 1);
        }
#pragma unroll
        for (int j = 0; j < 16; ++j) {
            if (pib[j] < SEGCAP)
                gbuf[((unsigned)bk[j] * NPB + b) * SEGCAP + pib[j]] = pay[j];
        }
        __syncthreads();                 // histogram complete
        for (int i = t; i < NBKT; i += 256) {
            int c = cur[i];
            if (c > SEGCAP) c = SEGCAP;
            cnt[i * NPB + b] = (unsigned short)c;
        }
    } else if (b < NPB + 64) {           // ---- convw ----
        int u = (b - NPB) * 256 + t;
        if (u < 64 * 128) {              // W1 [64][128] -> W1T [128][64]
            int k = u >> 7, n = u & 127;
            W1T[n * 64 + k] = __float2bfloat16(W1[u]);
        } else {                         // W2 [128][64] -> W2T [64][128]
            int v = u - 64 * 128;
            int k = v >> 6, n = v & 63;
            W2T[n * 128 + k] = __float2bfloat16(W2[v]);
        }
    } else {                             // ---- transWfc ----
        float (*ts)[33] = (float(*)[33])smem;
        const int bid2 = b - (NPB + 64);
        const int n0 = (bid2 % 56) * 32, k0 = (bid2 / 56) * 32;
        const int tx = t & 31, ty = t >> 5;
        const bool nok = (n0 + tx) < 1728;
#pragma unroll
        for (int j = 0; j < 4; ++j)
            ts[ty + j * 8][tx] =
                nok ? Wfc[(long)(k0 + ty + j * 8) * 1728 + n0 + tx] : 0.0f;
        __syncthreads();
#pragma unroll
        for (int j = 0; j < 4; ++j)
            WfcT[(long)(n0 + ty + j * 8) * 1920 + k0 + tx] =
                __float2bfloat16(ts[tx][ty + j * 8]);
    }
}

// ---- pass 2: per-bucket CSR build + dinv + FUSED x->bf16 pre-scale --------
// v2: idx->segment LOOKUP TABLE in LDS (built once per block) replaces the
// per-edge 8-step binary search over segment offsets.
__global__ __launch_bounds__(256) void k_bcsr(
        const unsigned short* __restrict__ cnt,
        const unsigned* __restrict__ gbuf,
        int* __restrict__ adj, unsigned* __restrict__ co,
        float* __restrict__ dinv,
        const float* __restrict__ x, bf16* __restrict__ xb) {
    __shared__ int hist[256];
    __shared__ int arr[256];
    __shared__ int exc[256];
    __shared__ int soff[256];
    __shared__ float dinvs[256];
    __shared__ unsigned char segtab[BCAP];   // idx -> segment (t<240 fits u8)
    const int b = blockIdx.x, t = threadIdx.x;
    hist[t] = 0;

    // segment counts scan (240 segments, exclusive offsets in soff)
    const int myc = (t < NPB) ? (int)cnt[b * NPB + t] : 0;
    arr[t] = myc;
    __syncthreads();
    for (int d = 1; d < 256; d <<= 1) {
        int v = (t >= d) ? arr[t - d] : 0;
        __syncthreads();
        arr[t] += v;
        __syncthreads();
    }
    soff[t] = arr[t] - myc;
    __syncthreads();
    int E = arr[255];
    if (E > BCAP) E = BCAP;

    // build idx -> segment table (mean 8.5, max SEGCAP iterations)
    if (t < NPB) {
        const int base = soff[t];
        for (int i = 0; i < myc && base + i < BCAP; ++i)
            segtab[base + i] = (unsigned char)t;
    }
    __syncthreads();

    int dl[10], sv[10];
    short pb[10];
    int n = 0;
    for (int idx = t; idx < E; idx += 256) {
        const int seg = segtab[idx];
        unsigned p = gbuf[((unsigned)b * NPB + seg) * SEGCAP + (idx - soff[seg])];
        dl[n] = p & 255;
        sv[n] = (int)(p >> 8);
        pb[n] = (short)atomicAdd(&hist[dl[n]], 1);
        ++n;
    }
    __syncthreads();
    const int cnt_t = hist[t];
    arr[t] = cnt_t;
    __syncthreads();
    for (int d = 1; d < 256; d <<= 1) {      // dest-local inclusive scan
        int v = (t >= d) ? arr[t - d] : 0;
        __syncthreads();
        arr[t] += v;
        __syncthreads();
    }
    const int ex = arr[t] - cnt_t;           // exclusive offset
    exc[t] = ex;
    const int node = b * 256 + t;
    co[node] = ((unsigned)ex << 16) | (unsigned)cnt_t;
    const float di = rsqrtf((float)cnt_t + 1.0f);
    dinv[node] = di;
    dinvs[t] = di;
    __syncthreads();
    for (int j = 0; j < n; ++j)
        adj[b * BCAP + exc[dl[j]] + pb[j]] = sv[j];

    // fused convert: this block's 256 node rows, 4 floats/thread/iter
    const long xbase = (long)b * 256 * 64;
    for (int r = 0; r < 16; ++r) {
        int u = r * 256 + t;                 // 0..4095
        int nl = u >> 4;                     // node-local
        const float4 v = ((const float4*)(x + xbase))[u];
        const float d2 = dinvs[nl];
        bf16* o = xb + xbase + u * 4;
        o[0] = __float2bfloat16(d2 * v.x);
        o[1] = __float2bfloat16(d2 * v.y);
        o[2] = __float2bfloat16(d2 * v.z);
        o[3] = __float2bfloat16(d2 * v.w);
    }
}

// ------- aggregation on pre-scaled features: out = di*(self + sum nbrs) -----
// (round-7/11 best variant: single node per 16-lane group, 8 uint2 loads in
// flight, ok-masked. Two widening attempts (R9, R12) both regressed ->
// LLC-random-BW-bound; this form is the measured floor.)
template <bool BIAS_RELU>
__global__ __launch_bounds__(256) void k_agg(const bf16* __restrict__ xb,
                                             const float* __restrict__ dinv,
                                             const unsigned* __restrict__ co,
                                             const int* __restrict__ adj,
                                             const float* __restrict__ bias,
                                             bf16* __restrict__ out) {
    const int wave = threadIdx.x >> 6, lane = threadIdx.x & 63;
    const int sub = lane >> 4, l16 = lane & 15;
    const int node = blockIdx.x * 16 + wave * 4 + sub;

    const float di = dinv[node];
    const unsigned c_ = co[node];
    int c = (int)(c_ & 0xffffu);
    if (c > 32) c = 32;
    const int* al = adj + (node >> 8) * BCAP + (c_ >> 16);
    int sl  = (l16 < c)      ? al[l16]      : 0;
    int sl2 = (16 + l16 < c) ? al[16 + l16] : 0;

    const uint2 us = *(const uint2*)(xb + ((long)node << 6) + (l16 << 2));
    float a0 = bflo(us.x), a1 = bfhi(us.x);
    float a2 = bflo(us.y), a3 = bfhi(us.y);

    for (int p0 = 0; p0 < c; p0 += 8) {
        uint2 uu[8];
#pragma unroll
        for (int j = 0; j < 8; ++j) {
            int p = p0 + j;
            bool ok = p < c;                 // uniform within 16-lane group
            int sv = (p < 16) ? sl : sl2;
            int s = __shfl(sv, p & 15, 16);
            uint2 u = *(const uint2*)(xb + ((long)s << 6) + (l16 << 2));
            uu[j].x = ok ? u.x : 0u;
            uu[j].y = ok ? u.y : 0u;
        }
#pragma unroll
        for (int j = 0; j < 8; ++j) {
            a0 += bflo(uu[j].x);
            a1 += bfhi(uu[j].x);
            a2 += bflo(uu[j].y);
            a3 += bfhi(uu[j].y);
        }
    }

    float r0 = di * a0, r1 = di * a1, r2 = di * a2, r3 = di * a3;
    if (BIAS_RELU) {
        r0 = fmaxf(r0 + bias[l16 * 4 + 0], 0.0f);
        r1 = fmaxf(r1 + bias[l16 * 4 + 1], 0.0f);
        r2 = fmaxf(r2 + bias[l16 * 4 + 2], 0.0f);
        r3 = fmaxf(r3 + bias[l16 * 4 + 3], 0.0f);
    }
    bf16* o = out + ((long)node << 6) + (l16 << 2);
    o[0] = __float2bfloat16(r0);
    o[1] = __float2bfloat16(r1);
    o[2] = __float2bfloat16(r2);
    o[3] = __float2bfloat16(r3);
}

// -------- fused MLP: g = dinv (.) ( relu(xa@W1 + b1) @ W2 )  ----------------
__global__ __launch_bounds__(256) void k_mlp(const bf16* __restrict__ xa,
                                             const bf16* __restrict__ W1T,
                                             const bf16* __restrict__ W2T,
                                             const float* __restrict__ b1,
                                             const float* __restrict__ dinv,
                                             bf16* __restrict__ g) {
    __shared__ __align__(16) bf16 As[128 * 64];    // row&7 chunk-XOR swizzle
    __shared__ __align__(16) bf16 C1s[128 * 136];
    const int tid = threadIdx.x;
    const int wave = tid >> 6, lane = tid & 63;
    const int quad = lane >> 4, l16 = lane & 15;
    const int bm = blockIdx.x * 128;
    const int wm = (wave & 1) * 64;
    const int wn1 = (wave >> 1) * 64;
    const int wn2 = (wave >> 1) * 32;

#pragma unroll
    for (int q = 0; q < 4; ++q) {
        int G = q * 256 + tid;
        int gc = (G & ~7) | ((G & 7) ^ ((G >> 3) & 7));
        gl_lds16(xa + (long)bm * 64 + gc * 8, As + ((q * 4 + wave) * 64) * 8);
    }
    short8 w1f[2][4];
#pragma unroll
    for (int kc = 0; kc < 2; ++kc)
#pragma unroll
        for (int in = 0; in < 4; ++in)
            w1f[kc][in] = *(const short8*)(W1T + (wn1 + in * 16 + l16) * 64 +
                                           kc * 32 + quad * 8);
    floatx4 acc1[4][4];
#pragma unroll
    for (int i = 0; i < 4; ++i)
#pragma unroll
        for (int j = 0; j < 4; ++j) acc1[i][j] = (floatx4){0.f, 0.f, 0.f, 0.f};
    __syncthreads();

#pragma unroll
    for (int kc = 0; kc < 2; ++kc)
#pragma unroll
        for (int im = 0; im < 4; ++im) {
            const int R = wm + im * 16 + l16;
            short8 af = *(const short8*)(As + R * 64 +
                                         (((kc * 4 + quad) ^ (R & 7)) * 8));
#pragma unroll
            for (int in = 0; in < 4; ++in)
                acc1[im][in] = __builtin_amdgcn_mfma_f32_16x16x32_bf16(
                    af, w1f[kc][in], acc1[im][in], 0, 0, 0);
        }

#pragma unroll
    for (int in = 0; in < 4; ++in) {
        const int col = wn1 + in * 16 + l16;
        const float bv = b1[col];
#pragma unroll
        for (int im = 0; im < 4; ++im) {
            const int row = wm + im * 16 + quad * 4;
#pragma unroll
            for (int r = 0; r < 4; ++r)
                C1s[(row + r) * 136 + col] =
                    __float2bfloat16(fmaxf(acc1[im][in][r] + bv, 0.0f));
        }
    }
    short8 w2f[4][2];
#pragma unroll
    for (int kc = 0; kc < 4; ++kc)
#pragma unroll
        for (int in = 0; in < 2; ++in)
            w2f[kc][in] = *(const short8*)(W2T + (wn2 + in * 16 + l16) * 128 +
                                           kc * 32 + quad * 8);
    floatx4 acc2[4][2];
#pragma unroll
    for (int i = 0; i < 4; ++i)
#pragma unroll
        for (int j = 0; j < 2; ++j) acc2[i][j] = (floatx4){0.f, 0.f, 0.f, 0.f};
    __syncthreads();

#pragma unroll
    for (int kc = 0; kc < 4; ++kc)
#pragma unroll
        for (int im = 0; im < 4; ++im) {
            short8 af = *(const short8*)(C1s + (wm + im * 16 + l16) * 136 +
                                         kc * 32 + quad * 8);
#pragma unroll
            for (int in = 0; in < 2; ++in)
                acc2[im][in] = __builtin_amdgcn_mfma_f32_16x16x32_bf16(
                    af, w2f[kc][in], acc2[im][in], 0, 0, 0);
        }

    float dv[4][4];
#pragma unroll
    for (int im = 0; im < 4; ++im)
#pragma unroll
        for (int r = 0; r < 4; ++r)
            dv[im][r] = dinv[bm + wm + im * 16 + quad * 4 + r];

#pragma unroll
    for (int in = 0; in < 2; ++in) {
        const int col = wn2 + in * 16 + l16;
#pragma unroll
        for (int im = 0; im < 4; ++im) {
            const int row = bm + wm + im * 16 + quad * 4;
#pragma unroll
            for (int r = 0; r < 4; ++r)
                g[(long)(row + r) * 64 + col] =
                    __float2bfloat16(dv[im][r] * acc2[im][in][r]);
        }
    }
}

// ------ bf16 MFMA GEMM 128x128, BK=64 (half the barriers), 8 waves ----------
template <bool RELU, bool BIAS, typename OutT>
__global__ __launch_bounds__(512) void gemm_bt(const bf16* __restrict__ A,
                                               const bf16* __restrict__ BT,
                                               const float* __restrict__ bias,
                                               OutT* __restrict__ C,
                                               int M, int N, int K) {
    __shared__ __align__(16) bf16 As[2][128 * 64];
    __shared__ __align__(16) bf16 Bs[2][128 * 64];
    const int tid = threadIdx.x;
    const int wave = tid >> 6, lane = tid & 63;
    const int quad = lane >> 4, l16 = lane & 15;
    const int bid = blockIdx.x;
    const int bx = (bid & 7) * 4 + ((bid >> 3) & 3);   // M-tile
    const int by = bid >> 5;                           // N-tile
    const int bm = bx * 128, bn = by * 128;
    const int wm = (wave & 1) * 64, wn = (wave >> 1) * 32;

    floatx4 acc[4][2];
#pragma unroll
    for (int i = 0; i < 4; ++i)
#pragma unroll
        for (int j = 0; j < 2; ++j) acc[i][j] = (floatx4){0.f, 0.f, 0.f, 0.f};

    const int r8 = tid >> 3;   // row 0..63 (row+64 in second store)
    const int c8 = tid & 7;    // 16B chunk within 128B row
    const int slot = r8 * 64 + ((c8 ^ (r8 & 7)) * 8);   // shorts; (r8+64)&7==r8&7

    const bf16* gA0 = A + (long)(bm + r8) * K + c8 * 8;
    const bf16* gA1 = A + (long)(bm + r8 + 64) * K + c8 * 8;
    const bf16* gB0 = BT + (long)(bn + r8) * K + c8 * 8;
    const bf16* gB1 = BT + (long)(bn + r8 + 64) * K + c8 * 8;

    const int rsw = l16 & 7;
    const int NT = K >> 6;     // 30 K-steps of 64

    // ---- prologue: tile0 -> buf0; prefetch tile1 into regs ----
    uint4 ra0 = *(const uint4*)gA0;
    uint4 ra1 = *(const uint4*)gA1;
    uint4 rb0 = *(const uint4*)gB0;
    uint4 rb1 = *(const uint4*)gB1;
    *(uint4*)(As[0] + slot) = ra0;
    *(uint4*)(As[0] + 4096 + slot) = ra1;
    *(uint4*)(Bs[0] + slot) = rb0;
    *(uint4*)(Bs[0] + 4096 + slot) = rb1;
    ra0 = *(const uint4*)(gA0 + 64);
    ra1 = *(const uint4*)(gA1 + 64);
    rb0 = *(const uint4*)(gB0 + 64);
    rb1 = *(const uint4*)(gB1 + 64);
    __syncthreads();

    // regs hold tile t+1 at the top of step t; buf[t&1] holds tile t.
    for (int t = 0; t < NT; t += 2) {
        // ---- step t (even): compute buf0, write tile t+1 -> buf1 ----
        {
            short8 af[2][4], bfr[2][2];
#pragma unroll
            for (int kc = 0; kc < 2; ++kc) {
#pragma unroll
                for (int im = 0; im < 4; ++im)
                    af[kc][im] = *(const short8*)(
                        As[0] + (wm + im * 16 + l16) * 64 +
                        (((kc * 4 + quad) ^ rsw) * 8));
#pragma unroll
                for (int in = 0; in < 2; ++in)
                    bfr[kc][in] = *(const short8*)(
                        Bs[0] + (wn + in * 16 + l16) * 64 +
                        (((kc * 4 + quad) ^ rsw) * 8));
            }
            *(uint4*)(As[1] + slot) = ra0;            // tile t+1 (always exists)
            *(uint4*)(As[1] + 4096 + slot) = ra1;
            *(uint4*)(Bs[1] + slot) = rb0;
            *(uint4*)(Bs[1] + 4096 + slot) = rb1;
            if (t + 2 < NT) {                         // prefetch tile t+2
                ra0 = *(const uint4*)(gA0 + (t + 2) * 64);
                ra1 = *(const uint4*)(gA1 + (t + 2) * 64);
                rb0 = *(const uint4*)(gB0 + (t + 2) * 64);
                rb1 = *(const uint4*)(gB1 + (t + 2) * 64);
            }
#pragma unroll
            for (int kc = 0; kc < 2; ++kc)
#pragma unroll
                for (int im = 0; im < 4; ++im)
#pragma unroll
                    for (int in = 0; in < 2; ++in)
                        acc[im][in] = __builtin_amdgcn_mfma_f32_16x16x32_bf16(
                            af[kc][im], bfr[kc][in], acc[im][in], 0, 0, 0);
            __syncthreads();
        }
        // ---- step t+1 (odd): compute buf1, write tile t+2 -> buf0 ----
        {
            short8 af[2][4], bfr[2][2];
#pragma unroll
            for (int kc = 0; kc < 2; ++kc) {
#pragma unroll
                for (int im = 0; im < 4; ++im)
                    af[kc][im] = *(const short8*)(
                        As[1] + (wm + im * 16 + l16) * 64 +
                        (((kc * 4 + quad) ^ rsw) * 8));
#pragma unroll
                for (int in = 0; in < 2; ++in)
                    bfr[kc][in] = *(const short8*)(
                        Bs[1] + (wn + in * 16 + l16) * 64 +
                        (((kc * 4 + quad) ^ rsw) * 8));
            }
            if (t + 2 < NT) {                         // write tile t+2
                *(uint4*)(As[0] + slot) = ra0;
                *(uint4*)(As[0] + 4096 + slot) = ra1;
                *(uint4*)(Bs[0] + slot) = rb0;
                *(uint4*)(Bs[0] + 4096 + slot) = rb1;
            }
            if (t + 3 < NT) {                         // prefetch tile t+3
                ra0 = *(const uint4*)(gA0 + (t + 3) * 64);
                ra1 = *(const uint4*)(gA1 + (t + 3) * 64);
                rb0 = *(const uint4*)(gB0 + (t + 3) * 64);
                rb1 = *(const uint4*)(gB1 + (t + 3) * 64);
            }
#pragma unroll
            for (int kc = 0; kc < 2; ++kc)
#pragma unroll
                for (int im = 0; im < 4; ++im)
#pragma unroll
                    for (int in = 0; in < 2; ++in)
                        acc[im][in] = __builtin_amdgcn_mfma_f32_16x16x32_bf16(
                            af[kc][im], bfr[kc][in], acc[im][in], 0, 0, 0);
            __syncthreads();
        }
    }

#pragma unroll
    for (int in = 0; in < 2; ++in) {
        int gcol = bn + wn + in * 16 + l16;
        bool wok = gcol < N;
        float bv = (BIAS && wok) ? bias[gcol] : 0.0f;
#pragma unroll
        for (int im = 0; im < 4; ++im) {
            int mrow = bm + wm + im * 16 + quad * 4;
#pragma unroll
            for (int r = 0; r < 4; ++r) {
                float v = acc[im][in][r] + bv;
                if (RELU) v = fmaxf(v, 0.0f);
                if (wok) {
                    if constexpr (sizeof(OutT) == 2)
                        C[(long)(mrow + r) * N + gcol] = __float2bfloat16(v);
                    else
                        C[(long)(mrow + r) * N + gcol] = v;
                }
            }
        }
    }
}

// ---------------- driver (6 launches, no memset) ----------------
extern "C" void kernel_launch(void* const* d_in, const int* in_sizes, int n_in,
                              void* d_out, int out_size, void* d_ws, size_t ws_size,
                              hipStream_t stream) {
    const float* x   = (const float*)d_in[0];
    const int*   ei  = (const int*)d_in[1];
    const float* W1  = (const float*)d_in[2];
    const float* b1  = (const float*)d_in[3];
    const float* W2  = (const float*)d_in[4];
    const float* b2  = (const float*)d_in[5];
    const float* Wfc = (const float*)d_in[6];
    const float* bfc = (const float*)d_in[7];

    char* p = (char*)d_ws;
    unsigned short* cnt = (unsigned short*)p; p += (size_t)NBKT * NPB * 2; // 230400
    int*      adj  = (int*)p;      p += (size_t)NBKT * BCAP * 4;
    unsigned* co   = (unsigned*)p; p += (size_t)N_NODES * 4;
    float*    dinv = (float*)p;    p += (size_t)N_NODES * 4;
    bf16*     xb   = (bf16*)p;     p += (size_t)N_NODES * 64 * 2;
    // union: gbuf (18.43 MB, used by psort/bcsr only) overlays xa+g (31.4 MB)
    char* uni = p;
    unsigned* gbuf = (unsigned*)uni;                       // NBKT*NPB*SEGCAP*4
    bf16*     xa   = (bf16*)uni;
    bf16*     g    = (bf16*)(uni + (size_t)N_NODES * 64 * 2);
    p = uni + 2 * (size_t)N_NODES * 64 * 2;
    bf16*     h2   = (bf16*)p;     p += (size_t)N_NODES * 64 * 2;
    bf16*     W1T  = (bf16*)p;     p += 128 * 64 * 2;
    bf16*     W2T  = (bf16*)p;     p += 64 * 128 * 2;
    bf16*     WfcT = (bf16*)p;     p += (size_t)NPAD * 1920 * 2;

    // psort (private segments, no atomics) + convw + transWfc fused
    k_psort_prep<<<NPB + 64 + 3360, 256, 0, stream>>>(ei, cnt, gbuf,
                                                      W1, W2, Wfc,
                                                      W1T, W2T, WfcT);
    // CSR build + dinv + fused x->bf16 pre-scale (done with gbuf afterwards)
    k_bcsr<<<NBKT, 256, 0, stream>>>(cnt, gbuf, adj, co, dinv, x, xb);

    // xa = A_hat * x  (weight-free gather-sum on pre-scaled xb)
    k_agg<false><<<N_NODES / 16, 256, 0, stream>>>(xb, dinv, co, adj, nullptr, xa);
    // g = dinv (.) ( relu(xa@W1 + b1) @ W2 )
    k_mlp<<<N_NODES / 128, 256, 0, stream>>>(xa, W1T, W2T, b1, dinv, g);
    // h2 = relu(di*(g[d]+sum g[s]) + b2)
    k_agg<true><<<N_NODES / 16, 256, 0, stream>>>(g, dinv, co, adj, b2, h2);
    // out = h2.reshape(4096,1920) @ Wfc + bfc  (XCD-affine 1-D grid: 32x14=448)
    gemm_bt<false, true, float><<<448, 512, 0, stream>>>(
        h2, WfcT, bfc, (float*)d_out, 4096, 1728, 1920);
}